// Round 8
// baseline (412.969 us; speedup 1.0000x reference)
//
#include <hip/hip_runtime.h>

// MaxUnpooling2D scatter-add via LDS-local multisplit binning.
// updates [8,256,256,64] f32, mask int32 (flat index into [512*512*64] plane).
// out [8,512,512,64] f32, duplicates sum.
//
// dest flat (within batch plane) = (m & ~63) | c, c = element's own channel.
// bucket (global) = batch*1024 + (m>>14): 256 output pixels = 64 KB region.
// local idx in bucket = (m & 0x3FC0) | c, 14 bits.
//
// bin16k: TILE=16384 via 128 KB dynamic LDS. Reservations are rounded up to
// multiples of 8 records (64 B) and pad slots are written as {0, +0.0f}
// (numeric no-op in accum) -> every record cache line is written fully by
// exactly ONE workgroup: no partial-line RMW, no cross-XCD line sharing.

static constexpr int PER_B   = 1 << 22;            // 4,194,304 elems/batch
static constexpr int NB      = 8;
static constexpr int N_ELEM  = NB * PER_B;         // 33,554,432
static constexpr int BPB     = 1024;               // buckets per batch
static constexpr int NBUCK   = NB * BPB;           // 8192
static constexpr int CAP     = 5504;               // padded mean ~4992 + ~7.5 sigma; mult of 8
static constexpr int TILE    = 16384;              // elements per workgroup
static constexpr int EPT     = TILE / 4 / 1024;    // 4 vec4 loads per thread
static constexpr int BS      = 1024;               // threads per workgroup (16 waves)
static constexpr size_t CUR_BYTES = (size_t)NBUCK * 64;        // 1 cursor per 64B line
static constexpr size_t REC_BYTES = (size_t)NBUCK * CAP * 8;   // 360.7 MB (ws ~2 GiB)
static constexpr size_t SREC_BYTES = (size_t)TILE * 8;         // 128 KB dynamic LDS

typedef int      i4v __attribute__((ext_vector_type(4)));
typedef float    f4v __attribute__((ext_vector_type(4)));
typedef unsigned u2v __attribute__((ext_vector_type(2)));

// ---- Phase 1: zero cursor lines (512 KB) ----------------------------------
__global__ __launch_bounds__(256)
void zero_cur(uint4* __restrict__ cur) {
    cur[blockIdx.x * 256 + threadIdx.x] = make_uint4(0u, 0u, 0u, 0u);
}

// ---- Phase 2: LDS multisplit -> per-bucket 64B-aligned record runs --------
// 1024 threads, 16 elems/thread, 128 KB dynamic srec -> 1 WG/CU, 16 waves.
__global__ __launch_bounds__(BS)
void bin16k(const float* __restrict__ upd,
            const int*  __restrict__ mask,
            unsigned*   __restrict__ cur,
            u2v*        __restrict__ rec) {
    __shared__ unsigned cnt[BPB];      // 4 KB
    __shared__ unsigned pfx[BPB];      // 4 KB exclusive prefix
    __shared__ int      bm[BPB];       // 4 KB  rec_base - pfx
    __shared__ unsigned wsum[16];      // wave partial sums
    extern __shared__ u2v srec[];      // 128 KB locally-sorted records

    const int t = threadIdx.x;
    const int tile0 = blockIdx.x * TILE;            // tile fully inside one batch
    const unsigned bb = (unsigned)(tile0 >> 22) << 10;  // global bucket base

    cnt[t] = 0;                                     // BPB == BS
    __syncthreads();

    // histogram with returned rank (mask kept in registers); NT loads
    i4v m4[EPT];
    unsigned rk[4 * EPT];
    const int vbase = (tile0 >> 2) + t;             // vec4 index, coalesced per j
    const i4v* mp = reinterpret_cast<const i4v*>(mask);
    #pragma unroll
    for (int j = 0; j < EPT; ++j)
        m4[j] = __builtin_nontemporal_load(&mp[vbase + BS * j]);
    #pragma unroll
    for (int j = 0; j < EPT; ++j) {
        #pragma unroll
        for (int q = 0; q < 4; ++q) {
            unsigned lb = ((unsigned)m4[j][q] >> 14) & 1023u;
            rk[4 * j + q] = atomicAdd(&cnt[lb], 1u);
        }
    }
    __syncthreads();

    // exclusive scan over cnt[1024]: wave64 shfl scan + cross-wave scan
    const int lane = t & 63, wid = t >> 6;
    unsigned v = cnt[t], x = v;
    #pragma unroll
    for (int off = 1; off < 64; off <<= 1) {
        unsigned y = __shfl_up(x, off, 64);
        if (lane >= off) x += y;
    }
    if (lane == 63) wsum[wid] = x;                  // wave totals
    __syncthreads();
    if (t < 16) {
        unsigned w = wsum[t];
        #pragma unroll
        for (int off = 1; off < 16; off <<= 1) {
            unsigned y = __shfl_up(w, off, 64);
            if (t >= off) w += y;
        }
        wsum[t] = w;                                // inclusive wave-prefix
    }
    __syncthreads();
    unsigned excl = x - v + (wid ? wsum[wid - 1] : 0u);
    pfx[t] = excl;

    // reservation: one bucket per thread; reserve n rounded up to 8 records
    // (64 B) so this WG's run owns whole cache lines exclusively.
    {
        unsigned n  = cnt[t];
        unsigned np = (n + 7u) & ~7u;
        unsigned gb = bb + (unsigned)t;
        unsigned pos = 0;
        if (n) pos = atomicAdd(&cur[(size_t)gb * 16], np);
        bm[t] = (int)(gb * (unsigned)CAP + pos) - (int)excl;
    }
    __syncthreads();

    // place records into srec in bucket-major order
    const f4v* up = reinterpret_cast<const f4v*>(upd);
    #pragma unroll
    for (int j = 0; j < EPT; ++j) {
        f4v u = __builtin_nontemporal_load(&up[vbase + BS * j]);
        int cbase = (4 * (t + BS * j)) & 63;        // channel of elem q=0
        #pragma unroll
        for (int q = 0; q < 4; ++q) {
            unsigned mm   = (unsigned)m4[j][q];
            unsigned lb   = (mm >> 14) & 1023u;
            unsigned lidx = (mm & 0x3FC0u) | (unsigned)(cbase + q);
            unsigned pos  = pfx[lb] + rk[4 * j + q];
            u2v e; e[0] = lidx | (lb << 14); e[1] = __float_as_uint(u[q]);
            srec[pos] = e;
        }
    }

    // pad slots [n, np) of this WG's run with {lidx=0, val=+0.0f}: accum adds
    // +0.0 at region offset 0 -> numeric no-op. Keeps lines fully written.
    {
        unsigned n  = cnt[t];
        unsigned np = (n + 7u) & ~7u;
        int start = bm[t] + (int)pfx[t];            // = gb*CAP + pos
        unsigned end = (bb + (unsigned)t + 1u) * (unsigned)CAP;
        for (unsigned j = n; j < np; ++j) {
            unsigned d = (unsigned)start + j;
            if (d < end) { u2v o; o[0] = 0u; o[1] = 0u; rec[d] = o; }
        }
    }
    __syncthreads();

    // copy out: consecutive k in same bucket -> consecutive global addresses
    #pragma unroll
    for (int j = 0; j < 4 * EPT; ++j) {
        int k = t + BS * j;
        u2v e = srec[k];
        unsigned lb = e[0] >> 14;
        int dst = bm[lb] + k;
        unsigned end = (bb + lb + 1u) * (unsigned)CAP;   // overflow guard
        if ((unsigned)dst < end) {
            u2v o; o[0] = e[0] & 16383u; o[1] = e[1];
            rec[dst] = o;
        }
    }
}

// ---- Phase 3: per-bucket LDS accumulate + dense nontemporal write ---------
// 1024 threads, 64 KB LDS -> 2 WG/CU = 32 waves/CU.
__global__ __launch_bounds__(BS)
void bucket_accum(const u2v*      __restrict__ rec,
                  const unsigned* __restrict__ cur,
                  float*          __restrict__ out) {
    __shared__ float lds[16384];       // 64 KB = 256 pixels x 64 C
    int bucket = blockIdx.x;
    int t = threadIdx.x;

    f4v* lds4 = reinterpret_cast<f4v*>(lds);
    f4v z = {0.f, 0.f, 0.f, 0.f};
    #pragma unroll
    for (int k = 0; k < 4; ++k)
        lds4[t + BS * k] = z;
    __syncthreads();

    unsigned n = cur[(size_t)bucket * 16];          // padded total
    if (n > (unsigned)CAP) n = CAP;
    const u2v* r = rec + (size_t)bucket * CAP;
    for (unsigned k = t; k < n; k += BS) {
        u2v e = __builtin_nontemporal_load(&r[k]);   // read once, don't re-cache
        atomicAdd(&lds[e[0] & 16383u], __uint_as_float(e[1]));
    }
    __syncthreads();

    size_t obase = ((size_t)(bucket >> 10) << 24)     // batch plane
                 + ((size_t)(bucket & 1023) << 14);   // 256-pixel block
    f4v* out4 = reinterpret_cast<f4v*>(out + obase);
    #pragma unroll
    for (int k = 0; k < 4; ++k)
        __builtin_nontemporal_store(lds4[t + BS * k], &out4[t + BS * k]);
}

// ---- Fallback: direct atomic scatter (round-1) ----------------------------
__global__ void unpool_scatter(const float* __restrict__ upd,
                               const int*  __restrict__ mask,
                               float*      __restrict__ out) {
    int i = blockIdx.x * blockDim.x + threadIdx.x;
    int base = i << 2;
    if (base >= N_ELEM) return;
    const int4   m = reinterpret_cast<const int4*>(mask)[i];
    const float4 u = reinterpret_cast<const float4*>(upd)[i];
    int b = base >> 22;
    int c = base & 63;
    size_t obase = ((size_t)b << 24) + c;
    atomicAdd(&out[obase + (size_t)(m.x & ~63)    ], u.x);
    atomicAdd(&out[obase + (size_t)(m.y & ~63) + 1], u.y);
    atomicAdd(&out[obase + (size_t)(m.z & ~63) + 2], u.z);
    atomicAdd(&out[obase + (size_t)(m.w & ~63) + 3], u.w);
}

extern "C" void kernel_launch(void* const* d_in, const int* in_sizes, int n_in,
                              void* d_out, int out_size, void* d_ws, size_t ws_size,
                              hipStream_t stream) {
    const float* upd  = (const float*)d_in[0];
    const int*   mask = (const int*)d_in[1];
    float*       out  = (float*)d_out;

    if (ws_size < CUR_BYTES + REC_BYTES) {
        hipMemsetAsync(out, 0, (size_t)out_size * sizeof(float), stream);
        int n4 = N_ELEM / 4;
        unpool_scatter<<<(n4 + 255) / 256, 256, 0, stream>>>(upd, mask, out);
        return;
    }

    unsigned* cur = (unsigned*)d_ws;
    u2v*      rec = (u2v*)((char*)d_ws + CUR_BYTES);

    // Opt in to >64 KB dynamic LDS (gfx950: 160 KB/CU). Non-stream call,
    // graph-capture-safe; deterministic.
    (void)hipFuncSetAttribute(reinterpret_cast<const void*>(bin16k),
                              hipFuncAttributeMaxDynamicSharedMemorySize,
                              (int)SREC_BYTES);

    zero_cur<<<CUR_BYTES / (256 * 16), 256, 0, stream>>>((uint4*)cur);
    bin16k<<<N_ELEM / TILE, BS, SREC_BYTES, stream>>>(upd, mask, cur, rec);
    bucket_accum<<<NBUCK, BS, 0, stream>>>(rec, cur, out);
}

// Round 9
// 388.443 us; speedup vs baseline: 1.0631x; 1.0631x over previous
//
#include <hip/hip_runtime.h>

// MaxUnpooling2D scatter-add, fully deterministic two-phase (NO global atomics).
// updates [8,256,256,64] f32, mask int32 (flat index into [512*512*64] plane).
// out [8,512,512,64] f32, duplicates sum.
//
// dest flat (within batch plane) = (m & ~63) | c, c = element's own channel.
// bucket (global) = batch*1024 + (m>>14): 256 output pixels = 64 KB region.
// local idx in bucket = (m & 0x3FC0) | c, 14 bits.
//
// Phase A (bin16k): per 16384-elem tile, sort records by bucket in LDS and
//   write them as ONE dense contiguous 128 KB block (fully coalesced, whole
//   lines, single-owner) + a u16 per-bucket prefix table (2 KB/tile).
// Phase B (bucket_gather): per bucket, read its 256 run offsets from the
//   prefix table, scan run lengths in LDS, binary-search rank->run, gather
//   records, LDS-accumulate, dense NT write of the 64 KB output region.

static constexpr int PER_B  = 1 << 22;             // 4,194,304 elems/batch
static constexpr int NB     = 8;
static constexpr int N_ELEM = NB * PER_B;          // 33,554,432
static constexpr int BPB    = 1024;                // buckets per batch
static constexpr int NBUCK  = NB * BPB;            // 8192
static constexpr int TILE   = 16384;               // elements per bin WG
static constexpr int NTILE  = N_ELEM / TILE;       // 2048
static constexpr int TPB    = PER_B / TILE;        // 256 tiles per batch
static constexpr int EPT    = TILE / 4 / 1024;     // 4 vec4 loads per thread
static constexpr int BS     = 1024;                // threads per WG (16 waves)
static constexpr size_t PFX_BYTES  = (size_t)NTILE * BPB * 2;  // 4 MB
static constexpr size_t REC_BYTES  = (size_t)N_ELEM * 8;       // 268.4 MB exact
static constexpr size_t SREC_BYTES = (size_t)TILE * 8;         // 128 KB dynamic LDS

typedef int      i4v __attribute__((ext_vector_type(4)));
typedef float    f4v __attribute__((ext_vector_type(4)));
typedef unsigned u2v __attribute__((ext_vector_type(2)));

// ---- Phase A: LDS multisplit -> dense per-tile record block + prefix table
// 1024 threads, 16 elems/thread, 128 KB dynamic srec -> 1 WG/CU, 16 waves.
__global__ __launch_bounds__(BS)
void bin16k(const float* __restrict__ upd,
            const int*  __restrict__ mask,
            unsigned short* __restrict__ pfx_tab,
            u2v*        __restrict__ rec) {
    __shared__ unsigned cnt[BPB];      // 4 KB
    __shared__ unsigned pfx[BPB];      // 4 KB exclusive prefix
    __shared__ unsigned wsum[16];      // wave partial sums
    extern __shared__ u2v srec[];      // 128 KB locally-sorted records

    const int t = threadIdx.x;
    const int tile  = blockIdx.x;
    const int tile0 = tile * TILE;                  // tile fully inside one batch

    cnt[t] = 0;                                     // BPB == BS
    __syncthreads();

    // histogram with returned rank (mask kept in registers); NT loads
    i4v m4[EPT];
    unsigned rk[4 * EPT];
    const int vbase = (tile0 >> 2) + t;             // vec4 index, coalesced per j
    const i4v* mp = reinterpret_cast<const i4v*>(mask);
    #pragma unroll
    for (int j = 0; j < EPT; ++j)
        m4[j] = __builtin_nontemporal_load(&mp[vbase + BS * j]);
    #pragma unroll
    for (int j = 0; j < EPT; ++j) {
        #pragma unroll
        for (int q = 0; q < 4; ++q) {
            unsigned lb = ((unsigned)m4[j][q] >> 14) & 1023u;
            rk[4 * j + q] = atomicAdd(&cnt[lb], 1u);
        }
    }
    __syncthreads();

    // exclusive scan over cnt[1024]: wave64 shfl scan + cross-wave scan
    const int lane = t & 63, wid = t >> 6;
    unsigned v = cnt[t], x = v;
    #pragma unroll
    for (int off = 1; off < 64; off <<= 1) {
        unsigned y = __shfl_up(x, off, 64);
        if (lane >= off) x += y;
    }
    if (lane == 63) wsum[wid] = x;                  // wave totals
    __syncthreads();
    if (t < 16) {
        unsigned w = wsum[t];
        #pragma unroll
        for (int off = 1; off < 16; off <<= 1) {
            unsigned y = __shfl_up(w, off, 64);
            if (t >= off) w += y;
        }
        wsum[t] = w;                                // inclusive wave-prefix
    }
    __syncthreads();
    unsigned excl = x - v + (wid ? wsum[wid - 1] : 0u);
    pfx[t] = excl;
    // prefix table entry (u16, values <= 16384): coalesced 2 KB per tile
    pfx_tab[tile * BPB + t] = (unsigned short)excl;
    __syncthreads();

    // place records into srec in bucket-major order
    const f4v* up = reinterpret_cast<const f4v*>(upd);
    #pragma unroll
    for (int j = 0; j < EPT; ++j) {
        f4v u = __builtin_nontemporal_load(&up[vbase + BS * j]);
        int cbase = (4 * (t + BS * j)) & 63;        // channel of elem q=0
        #pragma unroll
        for (int q = 0; q < 4; ++q) {
            unsigned mm   = (unsigned)m4[j][q];
            unsigned lb   = (mm >> 14) & 1023u;
            unsigned lidx = (mm & 0x3FC0u) | (unsigned)(cbase + q);
            unsigned pos  = pfx[lb] + rk[4 * j + q];
            u2v e; e[0] = lidx; e[1] = __float_as_uint(u[q]);
            srec[pos] = e;
        }
    }
    __syncthreads();

    // dense copy-out: the whole sorted tile as one contiguous 128 KB block.
    // Plain cached stores (records should stay L2/L3-resident for gather).
    const uint4* s4 = reinterpret_cast<const uint4*>(srec);
    uint4* r4 = reinterpret_cast<uint4*>(rec + (size_t)tile0);
    #pragma unroll
    for (int j = 0; j < TILE / 2 / BS; ++j)         // 8 x 16 B per thread
        r4[t + BS * j] = s4[t + BS * j];
}

// ---- Phase B: per-bucket gather + LDS accumulate + dense NT write ---------
// 1024 threads, ~66 KB LDS -> 2 WG/CU = 32 waves/CU.
__global__ __launch_bounds__(BS)
void bucket_gather(const u2v* __restrict__ rec,
                   const unsigned short* __restrict__ pfx_tab,
                   float* __restrict__ out) {
    __shared__ float    lds[16384];    // 64 KB = 256 pixels x 64 C
    __shared__ unsigned rstart[TPB];   // run start (global record idx)
    __shared__ unsigned rpfx[TPB + 1]; // exclusive prefix of run lengths
    __shared__ unsigned ws2[4];

    const int t = threadIdx.x;
    const int bucket = blockIdx.x;
    const int batch  = bucket >> 10;
    const int b      = bucket & 1023;

    f4v* lds4 = reinterpret_cast<f4v*>(lds);
    f4v z = {0.f, 0.f, 0.f, 0.f};
    #pragma unroll
    for (int k = 0; k < 4; ++k)
        lds4[t + BS * k] = z;

    // load this bucket's 256 run offsets; scan lengths (threads 0..255 = 4 waves)
    unsigned x = 0, len = 0;
    if (t < TPB) {
        int tile = (batch << 8) + t;
        unsigned s = pfx_tab[tile * BPB + b];
        unsigned e = (b == BPB - 1) ? (unsigned)TILE : pfx_tab[tile * BPB + b + 1];
        rstart[t] = (unsigned)tile * TILE + s;
        len = e - s;
        x = len;
        #pragma unroll
        for (int off = 1; off < 64; off <<= 1) {
            unsigned y = __shfl_up(x, off, 64);
            if ((t & 63) >= off) x += y;
        }
        if ((t & 63) == 63) ws2[t >> 6] = x;        // wave totals
    }
    __syncthreads();
    if (t == 0) {                                   // tiny serial cross-wave scan
        unsigned a = 0;
        #pragma unroll
        for (int i = 0; i < 4; ++i) { unsigned w = ws2[i]; ws2[i] = a; a += w; }
    }
    __syncthreads();
    if (t < TPB) {
        rpfx[t] = x - len + ws2[t >> 6];
        if (t == TPB - 1) rpfx[TPB] = ws2[3] + x;   // total
    }
    __syncthreads();

    // gather: rank k -> run via binary search (8 LDS steps), coalesced-ish loads
    const unsigned T = rpfx[TPB];
    for (unsigned k = t; k < T; k += BS) {
        unsigned lo = 0, hi = TPB;
        while (hi - lo > 1) {
            unsigned mid = (lo + hi) >> 1;
            if (rpfx[mid] <= k) lo = mid; else hi = mid;
        }
        u2v e = __builtin_nontemporal_load(&rec[rstart[lo] + (k - rpfx[lo])]);
        atomicAdd(&lds[e[0] & 16383u], __uint_as_float(e[1]));
    }
    __syncthreads();

    size_t obase = ((size_t)batch << 24) + ((size_t)b << 14);
    f4v* out4 = reinterpret_cast<f4v*>(out + obase);
    #pragma unroll
    for (int k = 0; k < 4; ++k)
        __builtin_nontemporal_store(lds4[t + BS * k], &out4[t + BS * k]);
}

// ---- Fallback: direct atomic scatter (round-1) ----------------------------
__global__ void unpool_scatter(const float* __restrict__ upd,
                               const int*  __restrict__ mask,
                               float*      __restrict__ out) {
    int i = blockIdx.x * blockDim.x + threadIdx.x;
    int base = i << 2;
    if (base >= N_ELEM) return;
    const int4   m = reinterpret_cast<const int4*>(mask)[i];
    const float4 u = reinterpret_cast<const float4*>(upd)[i];
    int b = base >> 22;
    int c = base & 63;
    size_t obase = ((size_t)b << 24) + c;
    atomicAdd(&out[obase + (size_t)(m.x & ~63)    ], u.x);
    atomicAdd(&out[obase + (size_t)(m.y & ~63) + 1], u.y);
    atomicAdd(&out[obase + (size_t)(m.z & ~63) + 2], u.z);
    atomicAdd(&out[obase + (size_t)(m.w & ~63) + 3], u.w);
}

extern "C" void kernel_launch(void* const* d_in, const int* in_sizes, int n_in,
                              void* d_out, int out_size, void* d_ws, size_t ws_size,
                              hipStream_t stream) {
    const float* upd  = (const float*)d_in[0];
    const int*   mask = (const int*)d_in[1];
    float*       out  = (float*)d_out;

    if (ws_size < PFX_BYTES + REC_BYTES) {
        hipMemsetAsync(out, 0, (size_t)out_size * sizeof(float), stream);
        int n4 = N_ELEM / 4;
        unpool_scatter<<<(n4 + 255) / 256, 256, 0, stream>>>(upd, mask, out);
        return;
    }

    unsigned short* pfx_tab = (unsigned short*)d_ws;
    u2v*            rec     = (u2v*)((char*)d_ws + PFX_BYTES);

    // Opt in to >64 KB dynamic LDS (gfx950: 160 KB/CU). Non-stream call,
    // graph-capture-safe; deterministic.
    (void)hipFuncSetAttribute(reinterpret_cast<const void*>(bin16k),
                              hipFuncAttributeMaxDynamicSharedMemorySize,
                              (int)SREC_BYTES);

    bin16k<<<NTILE, BS, SREC_BYTES, stream>>>(upd, mask, pfx_tab, rec);
    bucket_gather<<<NBUCK, BS, 0, stream>>>(rec, pfx_tab, out);
}

// Round 10
// 382.576 us; speedup vs baseline: 1.0794x; 1.0153x over previous
//
#include <hip/hip_runtime.h>

// MaxUnpooling2D scatter-add, fully deterministic two-phase (NO global atomics).
// updates [8,256,256,64] f32, mask int32 (flat index into [512*512*64] plane).
// out [8,512,512,64] f32, duplicates sum.
//
// dest flat (within batch plane) = (m & ~63) | c, c = element's own channel.
// bucket (global) = batch*1024 + (m>>14): 256 output pixels = 64 KB region.
// local idx in bucket = (m & 0x3FC0) | c, 14 bits.
//
// Phase A (bin16k): per 16384-elem tile, sort records by bucket in LDS and
//   write them as ONE dense contiguous 128 KB block (fully coalesced, whole
//   lines, single-owner) + a u16 per-bucket prefix table (2 KB/tile).
// Phase B (bucket_gather): per bucket, read its 256 run offsets, scan run
//   lengths in LDS, then each WAVE owns 16 consecutive runs and walks its
//   rank range with a monotone run pointer (~1 LDS read/record, no binary
//   search), gathers records, LDS-accumulates, dense NT-writes 64 KB.

static constexpr int PER_B  = 1 << 22;             // 4,194,304 elems/batch
static constexpr int NB     = 8;
static constexpr int N_ELEM = NB * PER_B;          // 33,554,432
static constexpr int BPB    = 1024;                // buckets per batch
static constexpr int NBUCK  = NB * BPB;            // 8192
static constexpr int TILE   = 16384;               // elements per bin WG
static constexpr int NTILE  = N_ELEM / TILE;       // 2048
static constexpr int TPB    = PER_B / TILE;        // 256 tiles (runs) per batch
static constexpr int EPT    = TILE / 4 / 1024;     // 4 vec4 loads per thread
static constexpr int BS     = 1024;                // threads per WG (16 waves)
static constexpr int RPW    = TPB / 16;            // 16 runs per wave
static constexpr size_t PFX_BYTES  = (size_t)NTILE * BPB * 2;  // 4 MB
static constexpr size_t REC_BYTES  = (size_t)N_ELEM * 8;       // 268.4 MB exact
static constexpr size_t SREC_BYTES = (size_t)TILE * 8;         // 128 KB dynamic LDS

typedef int      i4v __attribute__((ext_vector_type(4)));
typedef float    f4v __attribute__((ext_vector_type(4)));
typedef unsigned u2v __attribute__((ext_vector_type(2)));

// ---- Phase A: LDS multisplit -> dense per-tile record block + prefix table
// 1024 threads, 16 elems/thread, 128 KB dynamic srec -> 1 WG/CU, 16 waves.
__global__ __launch_bounds__(BS)
void bin16k(const float* __restrict__ upd,
            const int*  __restrict__ mask,
            unsigned short* __restrict__ pfx_tab,
            u2v*        __restrict__ rec) {
    __shared__ unsigned cnt[BPB];      // 4 KB
    __shared__ unsigned pfx[BPB];      // 4 KB exclusive prefix
    __shared__ unsigned wsum[16];      // wave partial sums
    extern __shared__ u2v srec[];      // 128 KB locally-sorted records

    const int t = threadIdx.x;
    const int tile  = blockIdx.x;
    const int tile0 = tile * TILE;                  // tile fully inside one batch

    cnt[t] = 0;                                     // BPB == BS
    __syncthreads();

    // histogram with returned rank (mask kept in registers); NT loads
    i4v m4[EPT];
    unsigned rk[4 * EPT];
    const int vbase = (tile0 >> 2) + t;             // vec4 index, coalesced per j
    const i4v* mp = reinterpret_cast<const i4v*>(mask);
    #pragma unroll
    for (int j = 0; j < EPT; ++j)
        m4[j] = __builtin_nontemporal_load(&mp[vbase + BS * j]);
    #pragma unroll
    for (int j = 0; j < EPT; ++j) {
        #pragma unroll
        for (int q = 0; q < 4; ++q) {
            unsigned lb = ((unsigned)m4[j][q] >> 14) & 1023u;
            rk[4 * j + q] = atomicAdd(&cnt[lb], 1u);
        }
    }
    __syncthreads();

    // exclusive scan over cnt[1024]: wave64 shfl scan + cross-wave scan
    const int lane = t & 63, wid = t >> 6;
    unsigned v = cnt[t], x = v;
    #pragma unroll
    for (int off = 1; off < 64; off <<= 1) {
        unsigned y = __shfl_up(x, off, 64);
        if (lane >= off) x += y;
    }
    if (lane == 63) wsum[wid] = x;                  // wave totals
    __syncthreads();
    if (t < 16) {
        unsigned w = wsum[t];
        #pragma unroll
        for (int off = 1; off < 16; off <<= 1) {
            unsigned y = __shfl_up(w, off, 64);
            if (t >= off) w += y;
        }
        wsum[t] = w;                                // inclusive wave-prefix
    }
    __syncthreads();
    unsigned excl = x - v + (wid ? wsum[wid - 1] : 0u);
    pfx[t] = excl;
    // prefix table entry (u16, values <= 16384): coalesced 2 KB per tile
    pfx_tab[tile * BPB + t] = (unsigned short)excl;
    __syncthreads();

    // place records into srec in bucket-major order
    const f4v* up = reinterpret_cast<const f4v*>(upd);
    #pragma unroll
    for (int j = 0; j < EPT; ++j) {
        f4v u = __builtin_nontemporal_load(&up[vbase + BS * j]);
        int cbase = (4 * (t + BS * j)) & 63;        // channel of elem q=0
        #pragma unroll
        for (int q = 0; q < 4; ++q) {
            unsigned mm   = (unsigned)m4[j][q];
            unsigned lb   = (mm >> 14) & 1023u;
            unsigned lidx = (mm & 0x3FC0u) | (unsigned)(cbase + q);
            unsigned pos  = pfx[lb] + rk[4 * j + q];
            u2v e; e[0] = lidx; e[1] = __float_as_uint(u[q]);
            srec[pos] = e;
        }
    }
    __syncthreads();

    // dense copy-out: the whole sorted tile as one contiguous 128 KB block.
    // Plain cached stores (records should stay L2/L3-resident for gather).
    const uint4* s4 = reinterpret_cast<const uint4*>(srec);
    uint4* r4 = reinterpret_cast<uint4*>(rec + (size_t)tile0);
    #pragma unroll
    for (int j = 0; j < TILE / 2 / BS; ++j)         // 8 x 16 B per thread
        r4[t + BS * j] = s4[t + BS * j];
}

// ---- Phase B: per-bucket gather + LDS accumulate + dense NT write ---------
// 1024 threads, ~66 KB LDS -> 2 WG/CU = 32 waves/CU.
// Each wave owns 16 consecutive runs; lanes walk consecutive ranks with a
// monotone run pointer (amortized ~1 LDS read per record).
__global__ __launch_bounds__(BS)
void bucket_gather(const u2v* __restrict__ rec,
                   const unsigned short* __restrict__ pfx_tab,
                   float* __restrict__ out) {
    __shared__ float    lds[16384];    // 64 KB = 256 pixels x 64 C
    __shared__ unsigned rstart[TPB];   // run start (global record idx)
    __shared__ unsigned rpfx[TPB + 1]; // exclusive prefix of run lengths
    __shared__ unsigned ws2[4];

    const int t = threadIdx.x;
    const int bucket = blockIdx.x;
    const int batch  = bucket >> 10;
    const int b      = bucket & 1023;

    f4v* lds4 = reinterpret_cast<f4v*>(lds);
    f4v z = {0.f, 0.f, 0.f, 0.f};
    #pragma unroll
    for (int k = 0; k < 4; ++k)
        lds4[t + BS * k] = z;

    // load this bucket's 256 run offsets; scan lengths (threads 0..255 = 4 waves)
    unsigned x = 0, len = 0;
    if (t < TPB) {
        int tile = (batch << 8) + t;
        unsigned s = pfx_tab[tile * BPB + b];
        unsigned e = (b == BPB - 1) ? (unsigned)TILE : pfx_tab[tile * BPB + b + 1];
        rstart[t] = (unsigned)tile * TILE + s;
        len = e - s;
        x = len;
        #pragma unroll
        for (int off = 1; off < 64; off <<= 1) {
            unsigned y = __shfl_up(x, off, 64);
            if ((t & 63) >= off) x += y;
        }
        if ((t & 63) == 63) ws2[t >> 6] = x;        // wave totals
    }
    __syncthreads();
    if (t == 0) {                                   // tiny serial cross-wave scan
        unsigned a = 0;
        #pragma unroll
        for (int i = 0; i < 4; ++i) { unsigned w = ws2[i]; ws2[i] = a; a += w; }
    }
    __syncthreads();
    if (t < TPB) {
        rpfx[t] = x - len + ws2[t >> 6];
        if (t == TPB - 1) rpfx[TPB] = ws2[3] + x;   // total
    }
    __syncthreads();

    // gather: wave w owns runs [RPW*w, RPW*(w+1)); lanes walk consecutive
    // ranks; run pointer advances monotonically (~1 LDS read per record).
    {
        const int w    = t >> 6;
        const int lane = t & 63;
        unsigned lo = (unsigned)(w * RPW);
        const unsigned k1 = rpfx[w * RPW + RPW];
        for (unsigned k = rpfx[w * RPW] + lane; k < k1; k += 64) {
            while (rpfx[lo + 1] <= k) ++lo;         // monotone advance
            u2v e = __builtin_nontemporal_load(&rec[rstart[lo] + (k - rpfx[lo])]);
            atomicAdd(&lds[e[0] & 16383u], __uint_as_float(e[1]));
        }
    }
    __syncthreads();

    size_t obase = ((size_t)batch << 24) + ((size_t)b << 14);
    f4v* out4 = reinterpret_cast<f4v*>(out + obase);
    #pragma unroll
    for (int k = 0; k < 4; ++k)
        __builtin_nontemporal_store(lds4[t + BS * k], &out4[t + BS * k]);
}

// ---- Fallback: direct atomic scatter (round-1) ----------------------------
__global__ void unpool_scatter(const float* __restrict__ upd,
                               const int*  __restrict__ mask,
                               float*      __restrict__ out) {
    int i = blockIdx.x * blockDim.x + threadIdx.x;
    int base = i << 2;
    if (base >= N_ELEM) return;
    const int4   m = reinterpret_cast<const int4*>(mask)[i];
    const float4 u = reinterpret_cast<const float4*>(upd)[i];
    int b = base >> 22;
    int c = base & 63;
    size_t obase = ((size_t)b << 24) + c;
    atomicAdd(&out[obase + (size_t)(m.x & ~63)    ], u.x);
    atomicAdd(&out[obase + (size_t)(m.y & ~63) + 1], u.y);
    atomicAdd(&out[obase + (size_t)(m.z & ~63) + 2], u.z);
    atomicAdd(&out[obase + (size_t)(m.w & ~63) + 3], u.w);
}

extern "C" void kernel_launch(void* const* d_in, const int* in_sizes, int n_in,
                              void* d_out, int out_size, void* d_ws, size_t ws_size,
                              hipStream_t stream) {
    const float* upd  = (const float*)d_in[0];
    const int*   mask = (const int*)d_in[1];
    float*       out  = (float*)d_out;

    if (ws_size < PFX_BYTES + REC_BYTES) {
        hipMemsetAsync(out, 0, (size_t)out_size * sizeof(float), stream);
        int n4 = N_ELEM / 4;
        unpool_scatter<<<(n4 + 255) / 256, 256, 0, stream>>>(upd, mask, out);
        return;
    }

    unsigned short* pfx_tab = (unsigned short*)d_ws;
    u2v*            rec     = (u2v*)((char*)d_ws + PFX_BYTES);

    // Opt in to >64 KB dynamic LDS (gfx950: 160 KB/CU). Non-stream call,
    // graph-capture-safe; deterministic.
    (void)hipFuncSetAttribute(reinterpret_cast<const void*>(bin16k),
                              hipFuncAttributeMaxDynamicSharedMemorySize,
                              (int)SREC_BYTES);

    bin16k<<<NTILE, BS, SREC_BYTES, stream>>>(upd, mask, pfx_tab, rec);
    bucket_gather<<<NBUCK, BS, 0, stream>>>(rec, pfx_tab, out);
}